// Round 7
// baseline (828.700 us; speedup 1.0000x reference)
//
#include <hip/hip_runtime.h>

#define NN 100000
#define DD 128
#define RR 4
#define EE 150000
#define HH 8
#define DK 16

#define NSEG (RR * NN)        // 400000
#define NEDGE (RR * EE)       // 600000
#define SCAN_BLK 256
#define SCAN_ELEMS 1024
#define SCAN_NB ((NSEG + SCAN_ELEMS - 1) / SCAN_ELEMS)   // 391
#define PAD_K 136             // bf16 row stride (272 B): frag reads spread banks

typedef short bf16x8 __attribute__((ext_vector_type(8)));
typedef float f32x4  __attribute__((ext_vector_type(4)));

// f32 -> bf16 round-to-nearest-even (bit pattern as ushort)
__device__ __forceinline__ unsigned short f2bf(float f) {
    unsigned u = __float_as_uint(f);
    return (unsigned short)((u + 0x7fffu + ((u >> 16) & 1u)) >> 16);
}
__device__ __forceinline__ float bflo(unsigned w) { return __uint_as_float(w << 16); }
__device__ __forceinline__ float bfhi(unsigned w) { return __uint_as_float(w & 0xffff0000u); }

// ---------- MFMA bf16 k/q/v projection (grid.y = matrix) ----------
// Tile: 64 X-rows x 128 out-cols. X,W staged once as bf16 in LDS (1 barrier,
// no LDS reuse). 4 waves in 2x2: wave = (wr: 32 X-rows, wc: 64 W-rows).
// mat 0: D = X * Wq^T -> q f32.  mat 1/2: D = W * X^T (swapped operands) so
// each lane holds 4 consecutive d-dims -> pack bf16 pairs in-lane into kv:
// kv[node][h] = 16 bf16 k | 16 bf16 v (64 B line, matches gather layout).
__global__ __launch_bounds__(256) void mfma_qkv(
    const float* __restrict__ X,
    const float* __restrict__ Wq, const float* __restrict__ Wk, const float* __restrict__ Wv,
    const float* __restrict__ bq, const float* __restrict__ bk, const float* __restrict__ bv,
    float* __restrict__ qout, unsigned* __restrict__ kv)
{
    const int tid = threadIdx.x;
    const int lane = tid & 63;
    const int wave = tid >> 6;
    const int wr = wave >> 1;            // X-row half (32 rows)
    const int wc = wave & 1;             // W-row half (64 rows)
    const long m0 = (long)blockIdx.x * 64;
    const int mat = blockIdx.y;
    const float* W    = (mat == 0) ? Wq : (mat == 1) ? Wk : Wv;
    const float* bias = (mat == 0) ? bq : (mat == 1) ? bk : bv;

    __shared__ short Xs[64 * PAD_K];
    __shared__ short Wsh[128 * PAD_K];

    // stage X tile 64x128 f32 -> bf16 (zero-fill OOB rows)
    #pragma unroll
    for (int i = 0; i < 8; ++i) {
        int f = tid + 256 * i;           // float4 slot in 64x32
        int row = f >> 5, c4 = f & 31;
        long m = m0 + row;
        float4 v = make_float4(0.f, 0.f, 0.f, 0.f);
        if (m < NN) v = ((const float4*)(X + m * DD))[c4];
        unsigned u0 = (unsigned)f2bf(v.x) | ((unsigned)f2bf(v.y) << 16);
        unsigned u1 = (unsigned)f2bf(v.z) | ((unsigned)f2bf(v.w) << 16);
        *(uint2*)&Xs[row * PAD_K + c4 * 4] = make_uint2(u0, u1);
    }
    // stage W 128x128 f32 -> bf16
    #pragma unroll
    for (int i = 0; i < 16; ++i) {
        int f = tid + 256 * i;
        int row = f >> 5, c4 = f & 31;
        float4 v = ((const float4*)(W + row * DD))[c4];
        unsigned u0 = (unsigned)f2bf(v.x) | ((unsigned)f2bf(v.y) << 16);
        unsigned u1 = (unsigned)f2bf(v.z) | ((unsigned)f2bf(v.w) << 16);
        *(uint2*)&Wsh[row * PAD_K + c4 * 4] = make_uint2(u0, u1);
    }
    __syncthreads();

    const int lrow = lane & 15;
    const int kg = lane >> 4;            // 0..3

    f32x4 acc[2][4];
    #pragma unroll
    for (int i = 0; i < 2; ++i)
        #pragma unroll
        for (int j = 0; j < 4; ++j) acc[i][j] = (f32x4){0.f, 0.f, 0.f, 0.f};

    #pragma unroll
    for (int ks = 0; ks < 4; ++ks) {
        const int kk = ks * 32 + kg * 8;
        bf16x8 xf[2], wf[4];
        #pragma unroll
        for (int i = 0; i < 2; ++i)
            xf[i] = *(const bf16x8*)&Xs[(wr * 32 + i * 16 + lrow) * PAD_K + kk];
        #pragma unroll
        for (int j = 0; j < 4; ++j)
            wf[j] = *(const bf16x8*)&Wsh[(wc * 64 + j * 16 + lrow) * PAD_K + kk];
        if (mat == 0) {
            #pragma unroll
            for (int i = 0; i < 2; ++i)
                #pragma unroll
                for (int j = 0; j < 4; ++j)
                    acc[i][j] = __builtin_amdgcn_mfma_f32_16x16x32_bf16(xf[i], wf[j], acc[i][j], 0, 0, 0);
        } else {
            #pragma unroll
            for (int i = 0; i < 2; ++i)
                #pragma unroll
                for (int j = 0; j < 4; ++j)
                    acc[i][j] = __builtin_amdgcn_mfma_f32_16x16x32_bf16(wf[j], xf[i], acc[i][j], 0, 0, 0);
        }
    }

    if (mat == 0) {
        // D rows = X rows, D cols = W rows(n). lane: col = lrow, row = kg*4+r
        #pragma unroll
        for (int j = 0; j < 4; ++j) {
            const int n = wc * 64 + j * 16 + lrow;
            const float bcol = bias[n];
            #pragma unroll
            for (int i = 0; i < 2; ++i) {
                #pragma unroll
                for (int r = 0; r < 4; ++r) {
                    long m = m0 + wr * 32 + i * 16 + kg * 4 + r;
                    if (m < NN) qout[m * DD + n] = acc[i][j][r] + bcol;
                }
            }
        }
    } else {
        // swapped: D rows = n (4 consecutive per lane), D cols = X rows m
        const unsigned slotu = (mat == 1) ? 0u : 8u;   // k at +0 uints, v at +8
        #pragma unroll
        for (int j = 0; j < 4; ++j) {
            const int nb = wc * 64 + j * 16 + kg * 4;  // d-base, 4 consecutive
            const float b0 = bias[nb + 0], b1 = bias[nb + 1];
            const float b2 = bias[nb + 2], b3 = bias[nb + 3];
            const int h = nb >> 4, d0 = nb & 15;
            #pragma unroll
            for (int i = 0; i < 2; ++i) {
                long m = m0 + wr * 32 + i * 16 + lrow;
                if (m < NN) {
                    unsigned u0 = (unsigned)f2bf(acc[i][j][0] + b0) | ((unsigned)f2bf(acc[i][j][1] + b1) << 16);
                    unsigned u1 = (unsigned)f2bf(acc[i][j][2] + b2) | ((unsigned)f2bf(acc[i][j][3] + b3) << 16);
                    *(uint2*)&kv[m * 128 + h * 16 + slotu + (d0 >> 1)] = make_uint2(u0, u1);
                }
            }
        }
    }
}

// ---------- MFMA bf16 output GEMM: out = (t/4)@Wa^T + ba, skip-gated ----------
__global__ __launch_bounds__(256) void mfma_out(
    const float* __restrict__ T, const float* __restrict__ Wa, const float* __restrict__ ba,
    float* __restrict__ out, const float* __restrict__ skip, const float* __restrict__ xres)
{
    const int tid = threadIdx.x;
    const int lane = tid & 63;
    const int wave = tid >> 6;
    const int wr = wave >> 1;
    const int wc = wave & 1;
    const long m0 = (long)blockIdx.x * 64;

    __shared__ short Xs[64 * PAD_K];
    __shared__ short Wsh[128 * PAD_K];

    #pragma unroll
    for (int i = 0; i < 8; ++i) {
        int f = tid + 256 * i;
        int row = f >> 5, c4 = f & 31;
        long m = m0 + row;
        float4 v = make_float4(0.f, 0.f, 0.f, 0.f);
        if (m < NN) v = ((const float4*)(T + m * DD))[c4];
        // fold cross-relation mean (1/4, exact in bf16) into the conversion
        unsigned u0 = (unsigned)f2bf(v.x * 0.25f) | ((unsigned)f2bf(v.y * 0.25f) << 16);
        unsigned u1 = (unsigned)f2bf(v.z * 0.25f) | ((unsigned)f2bf(v.w * 0.25f) << 16);
        *(uint2*)&Xs[row * PAD_K + c4 * 4] = make_uint2(u0, u1);
    }
    #pragma unroll
    for (int i = 0; i < 16; ++i) {
        int f = tid + 256 * i;
        int row = f >> 5, c4 = f & 31;
        float4 v = ((const float4*)(Wa + row * DD))[c4];
        unsigned u0 = (unsigned)f2bf(v.x) | ((unsigned)f2bf(v.y) << 16);
        unsigned u1 = (unsigned)f2bf(v.z) | ((unsigned)f2bf(v.w) << 16);
        *(uint2*)&Wsh[row * PAD_K + c4 * 4] = make_uint2(u0, u1);
    }
    __syncthreads();

    const int lrow = lane & 15;
    const int kg = lane >> 4;

    f32x4 acc[2][4];
    #pragma unroll
    for (int i = 0; i < 2; ++i)
        #pragma unroll
        for (int j = 0; j < 4; ++j) acc[i][j] = (f32x4){0.f, 0.f, 0.f, 0.f};

    #pragma unroll
    for (int ks = 0; ks < 4; ++ks) {
        const int kk = ks * 32 + kg * 8;
        bf16x8 xf[2], wf[4];
        #pragma unroll
        for (int i = 0; i < 2; ++i)
            xf[i] = *(const bf16x8*)&Xs[(wr * 32 + i * 16 + lrow) * PAD_K + kk];
        #pragma unroll
        for (int j = 0; j < 4; ++j)
            wf[j] = *(const bf16x8*)&Wsh[(wc * 64 + j * 16 + lrow) * PAD_K + kk];
        #pragma unroll
        for (int i = 0; i < 2; ++i)
            #pragma unroll
            for (int j = 0; j < 4; ++j)
                acc[i][j] = __builtin_amdgcn_mfma_f32_16x16x32_bf16(xf[i], wf[j], acc[i][j], 0, 0, 0);
    }

    const float s = 1.f / (1.f + __expf(-skip[0]));
    const float al = s, bt = 1.f - s;

    #pragma unroll
    for (int j = 0; j < 4; ++j) {
        const int n = wc * 64 + j * 16 + lrow;
        const float bcol = ba[n];
        #pragma unroll
        for (int i = 0; i < 2; ++i) {
            #pragma unroll
            for (int r = 0; r < 4; ++r) {
                long m = m0 + wr * 32 + i * 16 + kg * 4 + r;
                if (m < NN) {
                    long o = m * DD + n;
                    out[o] = __builtin_fmaf(xres[o], bt, (acc[i][j][r] + bcol) * al);
                }
            }
        }
    }
}

// ---------- CSR build: histogram -> scan -> fill ----------
// offs[] is IMMUTABLE after scan; csr_fill bumps cur[].

__global__ __launch_bounds__(256) void csr_hist(
    const int* __restrict__ edst, int* __restrict__ cnt)
{
    int idx = blockIdx.x * 256 + threadIdx.x;
    if (idx >= NEDGE) return;
    int r = idx / EE;
    atomicAdd(&cnt[r * NN + edst[idx]], 1);
}

__global__ __launch_bounds__(SCAN_BLK) void scan1(
    const int* __restrict__ cnt, int* __restrict__ offs, int* __restrict__ bsum)
{
    __shared__ int sh[SCAN_BLK];
    int blk = blockIdx.x, tid = threadIdx.x;
    int base = blk * SCAN_ELEMS + tid * 4;
    int v0 = 0, v1 = 0, v2 = 0, v3 = 0;
    if (base + 3 < NSEG) {
        int4 t = *(const int4*)(cnt + base);
        v0 = t.x; v1 = t.y; v2 = t.z; v3 = t.w;
    } else {
        if (base + 0 < NSEG) v0 = cnt[base + 0];
        if (base + 1 < NSEG) v1 = cnt[base + 1];
        if (base + 2 < NSEG) v2 = cnt[base + 2];
        if (base + 3 < NSEG) v3 = cnt[base + 3];
    }
    int tsum = v0 + v1 + v2 + v3;
    sh[tid] = tsum;
    __syncthreads();
    #pragma unroll
    for (int d = 1; d < SCAN_BLK; d <<= 1) {
        int x = (tid >= d) ? sh[tid - d] : 0;
        __syncthreads();
        sh[tid] += x;
        __syncthreads();
    }
    int excl = sh[tid] - tsum;
    int r0 = excl, r1 = r0 + v0, r2 = r1 + v1, r3 = r2 + v2;
    if (base + 3 < NSEG) {
        *(int4*)(offs + base) = make_int4(r0, r1, r2, r3);
    } else {
        if (base + 0 < NSEG) offs[base + 0] = r0;
        if (base + 1 < NSEG) offs[base + 1] = r1;
        if (base + 2 < NSEG) offs[base + 2] = r2;
        if (base + 3 < NSEG) offs[base + 3] = r3;
    }
    if (tid == SCAN_BLK - 1) bsum[blk] = sh[tid];
}

__global__ __launch_bounds__(512) void scan2(int* __restrict__ bsum)
{
    __shared__ int sh[512];
    int tid = threadIdx.x;
    int v = (tid < SCAN_NB) ? bsum[tid] : 0;
    sh[tid] = v;
    __syncthreads();
    #pragma unroll
    for (int d = 1; d < 512; d <<= 1) {
        int x = (tid >= d) ? sh[tid - d] : 0;
        __syncthreads();
        sh[tid] += x;
        __syncthreads();
    }
    if (tid < SCAN_NB) bsum[tid] = sh[tid] - v;   // exclusive block sums
}

__global__ __launch_bounds__(SCAN_BLK) void scan3(
    int* __restrict__ offs, int* __restrict__ cur, const int* __restrict__ bsum)
{
    int blk = blockIdx.x;
    int add = bsum[blk];
    int base = blk * SCAN_ELEMS + threadIdx.x * 4;
    #pragma unroll
    for (int j = 0; j < 4; ++j)
        if (base + j < NSEG) {
            int v = offs[base + j] + add;
            offs[base + j] = v;
            cur[base + j] = v;
        }
}

__global__ __launch_bounds__(256) void csr_fill(
    const int* __restrict__ esrc, const int* __restrict__ edst,
    int* __restrict__ cur, int* __restrict__ csr_src)
{
    int idx = blockIdx.x * 256 + threadIdx.x;
    if (idx >= NEDGE) return;
    int r = idx / EE;
    int pos = atomicAdd(&cur[r * NN + edst[idx]], 1);
    csr_src[pos] = esrc[idx];
}

// ---------- fused per-dst gather ----------
// thread = (dst,h). No LDS (A/M read from L2-resident globals) -> occupancy
// is VGPR-bound. Plain exp (no max shift): softmax is shift-invariant and
// |att| << 88 for these magnitudes, so f32 exp cannot overflow.
#define GT 256
__global__ __launch_bounds__(GT) void gather_agg(
    const unsigned* __restrict__ kv, const float* __restrict__ q,
    const int* __restrict__ csr_src, const int* __restrict__ offs,
    const float* __restrict__ rel_att, const float* __restrict__ rel_msg,
    const float* __restrict__ rel_pri, float* __restrict__ t)
{
    int gidx = blockIdx.x * GT + threadIdx.x;
    if (gidx >= NN * HH) return;
    const int dst = gidx >> 3, h = gidx & 7;

    float qh[16];
    {
        const float4* qp = (const float4*)(q + (long)dst * DD + h * DK);
        #pragma unroll
        for (int i = 0; i < 4; ++i) {
            float4 a = qp[i];
            qh[4*i] = a.x; qh[4*i+1] = a.y; qh[4*i+2] = a.z; qh[4*i+3] = a.w;
        }
    }

    float tacc[16];
    #pragma unroll
    for (int f = 0; f < 16; ++f) tacc[f] = 0.f;

    for (int r = 0; r < RR; ++r) {
        const int seg = r * NN + dst;
        const int beg = offs[seg];
        const int end = (seg == NSEG - 1) ? NEDGE : offs[seg + 1];
        if (end <= beg) continue;                 // empty mailbox contributes 0

        const float* A = rel_att + (((long)r * HH + h) << 8);
        const float* M = rel_msg + (((long)r * HH + h) << 8);
        const float pri = rel_pri[r * HH + h] * 0.25f;   // pri / sqrt(dk)

        float qbar[16];
        #pragma unroll
        for (int d = 0; d < 16; ++d) {
            float4 a0 = *(const float4*)(A + d * 16);
            float4 a1 = *(const float4*)(A + d * 16 + 4);
            float4 a2 = *(const float4*)(A + d * 16 + 8);
            float4 a3 = *(const float4*)(A + d * 16 + 12);
            float acc = a0.x * qh[0];
            acc = __builtin_fmaf(a0.y, qh[1], acc);
            acc = __builtin_fmaf(a0.z, qh[2], acc);
            acc = __builtin_fmaf(a0.w, qh[3], acc);
            acc = __builtin_fmaf(a1.x, qh[4], acc);
            acc = __builtin_fmaf(a1.y, qh[5], acc);
            acc = __builtin_fmaf(a1.z, qh[6], acc);
            acc = __builtin_fmaf(a1.w, qh[7], acc);
            acc = __builtin_fmaf(a2.x, qh[8], acc);
            acc = __builtin_fmaf(a2.y, qh[9], acc);
            acc = __builtin_fmaf(a2.z, qh[10], acc);
            acc = __builtin_fmaf(a2.w, qh[11], acc);
            acc = __builtin_fmaf(a3.x, qh[12], acc);
            acc = __builtin_fmaf(a3.y, qh[13], acc);
            acc = __builtin_fmaf(a3.z, qh[14], acc);
            acc = __builtin_fmaf(a3.w, qh[15], acc);
            qbar[d] = acc * pri;                  // fold pri/sqrt(dk) into qbar
        }

        float s = 0.f;
        float vb[16];
        #pragma unroll
        for (int f = 0; f < 16; ++f) vb[f] = 0.f;

        for (int e = beg; e < end; ++e) {
            int src = csr_src[e];
            const uint4* kvp = (const uint4*)kv + ((long)src * 32 + h * 4);
            uint4 ka = kvp[0], kb = kvp[1];
            uint4 va = kvp[2], vc = kvp[3];

            float att;
            att  = bflo(ka.x) * qbar[0];
            att = __builtin_fmaf(bfhi(ka.x), qbar[1], att);
            att = __builtin_fmaf(bflo(ka.y), qbar[2], att);
            att = __builtin_fmaf(bfhi(ka.y), qbar[3], att);
            att = __builtin_fmaf(bflo(ka.z), qbar[4], att);
            att = __builtin_fmaf(bfhi(ka.z), qbar[5], att);
            att = __builtin_fmaf(bflo(ka.w), qbar[6], att);
            att = __builtin_fmaf(bfhi(ka.w), qbar[7], att);
            att = __builtin_fmaf(bflo(kb.x), qbar[8], att);
            att = __builtin_fmaf(bfhi(kb.x), qbar[9], att);
            att = __builtin_fmaf(bflo(kb.y), qbar[10], att);
            att = __builtin_fmaf(bfhi(kb.y), qbar[11], att);
            att = __builtin_fmaf(bflo(kb.z), qbar[12], att);
            att = __builtin_fmaf(bfhi(kb.z), qbar[13], att);
            att = __builtin_fmaf(bflo(kb.w), qbar[14], att);
            att = __builtin_fmaf(bfhi(kb.w), qbar[15], att);

            float ea = __expf(att);
            s += ea;
            vb[0]  = __builtin_fmaf(ea, bflo(va.x), vb[0]);
            vb[1]  = __builtin_fmaf(ea, bfhi(va.x), vb[1]);
            vb[2]  = __builtin_fmaf(ea, bflo(va.y), vb[2]);
            vb[3]  = __builtin_fmaf(ea, bfhi(va.y), vb[3]);
            vb[4]  = __builtin_fmaf(ea, bflo(va.z), vb[4]);
            vb[5]  = __builtin_fmaf(ea, bfhi(va.z), vb[5]);
            vb[6]  = __builtin_fmaf(ea, bflo(va.w), vb[6]);
            vb[7]  = __builtin_fmaf(ea, bfhi(va.w), vb[7]);
            vb[8]  = __builtin_fmaf(ea, bflo(vc.x), vb[8]);
            vb[9]  = __builtin_fmaf(ea, bfhi(vc.x), vb[9]);
            vb[10] = __builtin_fmaf(ea, bflo(vc.y), vb[10]);
            vb[11] = __builtin_fmaf(ea, bfhi(vc.y), vb[11]);
            vb[12] = __builtin_fmaf(ea, bflo(vc.z), vb[12]);
            vb[13] = __builtin_fmaf(ea, bfhi(vc.z), vb[13]);
            vb[14] = __builtin_fmaf(ea, bflo(vc.w), vb[14]);
            vb[15] = __builtin_fmaf(ea, bfhi(vc.w), vb[15]);
        }

        float inv = 1.f / s;
        float u[16];
        #pragma unroll
        for (int f = 0; f < 16; ++f) u[f] = 0.f;
        #pragma unroll
        for (int d = 0; d < 16; ++d) {
            float vd = vb[d];
            float4 m0 = *(const float4*)(M + d * 16);
            float4 m1 = *(const float4*)(M + d * 16 + 4);
            float4 m2 = *(const float4*)(M + d * 16 + 8);
            float4 m3 = *(const float4*)(M + d * 16 + 12);
            u[0]  = __builtin_fmaf(vd, m0.x, u[0]);
            u[1]  = __builtin_fmaf(vd, m0.y, u[1]);
            u[2]  = __builtin_fmaf(vd, m0.z, u[2]);
            u[3]  = __builtin_fmaf(vd, m0.w, u[3]);
            u[4]  = __builtin_fmaf(vd, m1.x, u[4]);
            u[5]  = __builtin_fmaf(vd, m1.y, u[5]);
            u[6]  = __builtin_fmaf(vd, m1.z, u[6]);
            u[7]  = __builtin_fmaf(vd, m1.w, u[7]);
            u[8]  = __builtin_fmaf(vd, m2.x, u[8]);
            u[9]  = __builtin_fmaf(vd, m2.y, u[9]);
            u[10] = __builtin_fmaf(vd, m2.z, u[10]);
            u[11] = __builtin_fmaf(vd, m2.w, u[11]);
            u[12] = __builtin_fmaf(vd, m3.x, u[12]);
            u[13] = __builtin_fmaf(vd, m3.y, u[13]);
            u[14] = __builtin_fmaf(vd, m3.z, u[14]);
            u[15] = __builtin_fmaf(vd, m3.w, u[15]);
        }
        #pragma unroll
        for (int f = 0; f < 16; ++f)
            tacc[f] = __builtin_fmaf(u[f], inv, tacc[f]);
    }

    float* tp = t + (long)dst * DD + h * DK;
    #pragma unroll
    for (int i = 0; i < 4; ++i) {
        float4 o;
        o.x = tacc[4*i]; o.y = tacc[4*i+1]; o.z = tacc[4*i+2]; o.w = tacc[4*i+3];
        *(float4*)(tp + 4 * i) = o;
    }
}

extern "C" void kernel_launch(void* const* d_in, const int* in_sizes, int n_in,
                              void* d_out, int out_size, void* d_ws, size_t ws_size,
                              hipStream_t stream)
{
    const float* x   = (const float*)d_in[0];
    const int* esrc  = (const int*)d_in[1];
    const int* edst  = (const int*)d_in[2];
    const float* Wk  = (const float*)d_in[3];
    const float* bk  = (const float*)d_in[4];
    const float* Wq  = (const float*)d_in[5];
    const float* bq  = (const float*)d_in[6];
    const float* Wv  = (const float*)d_in[7];
    const float* bv  = (const float*)d_in[8];
    const float* Wa  = (const float*)d_in[9];
    const float* ba  = (const float*)d_in[10];
    const float* rel_att = (const float*)d_in[11];
    const float* rel_msg = (const float*)d_in[12];
    const float* rel_pri = (const float*)d_in[13];
    const float* skip    = (const float*)d_in[14];
    float* out = (float*)d_out;

    // ws: [q:ND][t:ND][kv:ND uints] [cnt:NSEG][offs:NSEG][cur:NSEG][bsum:512][csr:NEDGE]
    float* ws = (float*)d_ws;
    const long ND = (long)NN * DD;
    float* qbuf = ws;
    float* tbuf = ws + ND;
    unsigned* kvb = (unsigned*)(ws + 2 * ND);
    int* cnt  = (int*)(ws + 3 * ND);
    int* offs = cnt + NSEG;
    int* cur  = offs + NSEG;
    int* bsum = cur + NSEG;
    int* csr  = bsum + 512;

    hipMemsetAsync(cnt, 0, NSEG * sizeof(int), stream);

    const int gb = (NN + 63) / 64;   // 1563
    mfma_qkv<<<dim3(gb, 3), 256, 0, stream>>>(x, Wq, Wk, Wv, bq, bk, bv, qbuf, kvb);

    const int ebk = (NEDGE + 255) / 256;
    csr_hist<<<ebk, 256, 0, stream>>>(edst, cnt);
    scan1<<<SCAN_NB, SCAN_BLK, 0, stream>>>(cnt, offs, bsum);
    scan2<<<1, 512, 0, stream>>>(bsum);
    scan3<<<SCAN_NB, SCAN_BLK, 0, stream>>>(offs, cur, bsum);
    csr_fill<<<ebk, 256, 0, stream>>>(esrc, edst, cur, csr);

    gather_agg<<<(NN * HH + GT - 1) / GT, GT, 0, stream>>>(
        kvb, qbuf, csr, offs, rel_att, rel_msg, rel_pri, tbuf);

    mfma_out<<<gb, 256, 0, stream>>>(tbuf, Wa, ba, out, skip, x);
}

// Round 8
// 365.671 us; speedup vs baseline: 2.2662x; 2.2662x over previous
//
#include <hip/hip_runtime.h>

#define NN 100000
#define DD 128
#define RR 4
#define EE 150000
#define HH 8
#define DK 16

#define NSEG (RR * NN)        // 400000
#define NEDGE (RR * EE)       // 600000
#define SCAN_BLK 256
#define SCAN_ELEMS 1024
#define SCAN_NB ((NSEG + SCAN_ELEMS - 1) / SCAN_ELEMS)   // 391
#define PAD_K 136             // bf16 row stride (272 B): frag reads spread banks
#define MAT_U 132             // uints per 16x16 bf16 matrix: 128 data + 4 pad (528 B)

typedef short bf16x8 __attribute__((ext_vector_type(8)));
typedef float f32x4  __attribute__((ext_vector_type(4)));

// f32 -> bf16 round-to-nearest-even (bit pattern as ushort)
__device__ __forceinline__ unsigned short f2bf(float f) {
    unsigned u = __float_as_uint(f);
    return (unsigned short)((u + 0x7fffu + ((u >> 16) & 1u)) >> 16);
}
__device__ __forceinline__ float bflo(unsigned w) { return __uint_as_float(w << 16); }
__device__ __forceinline__ float bfhi(unsigned w) { return __uint_as_float(w & 0xffff0000u); }

// ---------- MFMA bf16 k/q/v projection (grid.y = matrix) ----------
// Tile: 64 X-rows x 128 out-cols. 4 waves in 2x2. mat 0: D = X*Wq^T -> q f32.
// mat 1/2: D = W*X^T (swapped) so each lane holds 4 consecutive d-dims ->
// pack bf16 pairs in-lane into kv[node][h] = 16 bf16 k | 16 bf16 v (64 B line).
__global__ __launch_bounds__(256) void mfma_qkv(
    const float* __restrict__ X,
    const float* __restrict__ Wq, const float* __restrict__ Wk, const float* __restrict__ Wv,
    const float* __restrict__ bq, const float* __restrict__ bk, const float* __restrict__ bv,
    float* __restrict__ qout, unsigned* __restrict__ kv)
{
    const int tid = threadIdx.x;
    const int lane = tid & 63;
    const int wave = tid >> 6;
    const int wr = wave >> 1;            // X-row half (32 rows)
    const int wc = wave & 1;             // W-row half (64 rows)
    const long m0 = (long)blockIdx.x * 64;
    const int mat = blockIdx.y;
    const float* W    = (mat == 0) ? Wq : (mat == 1) ? Wk : Wv;
    const float* bias = (mat == 0) ? bq : (mat == 1) ? bk : bv;

    __shared__ short Xs[64 * PAD_K];
    __shared__ short Wsh[128 * PAD_K];

    // stage X tile 64x128 f32 -> bf16 (zero-fill OOB rows)
    #pragma unroll
    for (int i = 0; i < 8; ++i) {
        int f = tid + 256 * i;           // float4 slot in 64x32
        int row = f >> 5, c4 = f & 31;
        long m = m0 + row;
        float4 v = make_float4(0.f, 0.f, 0.f, 0.f);
        if (m < NN) v = ((const float4*)(X + m * DD))[c4];
        unsigned u0 = (unsigned)f2bf(v.x) | ((unsigned)f2bf(v.y) << 16);
        unsigned u1 = (unsigned)f2bf(v.z) | ((unsigned)f2bf(v.w) << 16);
        *(uint2*)&Xs[row * PAD_K + c4 * 4] = make_uint2(u0, u1);
    }
    // stage W 128x128 f32 -> bf16
    #pragma unroll
    for (int i = 0; i < 16; ++i) {
        int f = tid + 256 * i;
        int row = f >> 5, c4 = f & 31;
        float4 v = ((const float4*)(W + row * DD))[c4];
        unsigned u0 = (unsigned)f2bf(v.x) | ((unsigned)f2bf(v.y) << 16);
        unsigned u1 = (unsigned)f2bf(v.z) | ((unsigned)f2bf(v.w) << 16);
        *(uint2*)&Wsh[row * PAD_K + c4 * 4] = make_uint2(u0, u1);
    }
    __syncthreads();

    const int lrow = lane & 15;
    const int kg = lane >> 4;            // 0..3

    f32x4 acc[2][4];
    #pragma unroll
    for (int i = 0; i < 2; ++i)
        #pragma unroll
        for (int j = 0; j < 4; ++j) acc[i][j] = (f32x4){0.f, 0.f, 0.f, 0.f};

    #pragma unroll
    for (int ks = 0; ks < 4; ++ks) {
        const int kk = ks * 32 + kg * 8;
        bf16x8 xf[2], wf[4];
        #pragma unroll
        for (int i = 0; i < 2; ++i)
            xf[i] = *(const bf16x8*)&Xs[(wr * 32 + i * 16 + lrow) * PAD_K + kk];
        #pragma unroll
        for (int j = 0; j < 4; ++j)
            wf[j] = *(const bf16x8*)&Wsh[(wc * 64 + j * 16 + lrow) * PAD_K + kk];
        if (mat == 0) {
            #pragma unroll
            for (int i = 0; i < 2; ++i)
                #pragma unroll
                for (int j = 0; j < 4; ++j)
                    acc[i][j] = __builtin_amdgcn_mfma_f32_16x16x32_bf16(xf[i], wf[j], acc[i][j], 0, 0, 0);
        } else {
            #pragma unroll
            for (int i = 0; i < 2; ++i)
                #pragma unroll
                for (int j = 0; j < 4; ++j)
                    acc[i][j] = __builtin_amdgcn_mfma_f32_16x16x32_bf16(wf[j], xf[i], acc[i][j], 0, 0, 0);
        }
    }

    if (mat == 0) {
        // D rows = X rows, D cols = W rows(n). lane: col = lrow, row = kg*4+r
        #pragma unroll
        for (int j = 0; j < 4; ++j) {
            const int n = wc * 64 + j * 16 + lrow;
            const float bcol = bias[n];
            #pragma unroll
            for (int i = 0; i < 2; ++i) {
                #pragma unroll
                for (int r = 0; r < 4; ++r) {
                    long m = m0 + wr * 32 + i * 16 + kg * 4 + r;
                    if (m < NN) qout[m * DD + n] = acc[i][j][r] + bcol;
                }
            }
        }
    } else {
        // swapped: D rows = n (4 consecutive per lane), D cols = X rows m
        const unsigned slotu = (mat == 1) ? 0u : 8u;   // k at +0 uints, v at +8
        #pragma unroll
        for (int j = 0; j < 4; ++j) {
            const int nb = wc * 64 + j * 16 + kg * 4;  // d-base, 4 consecutive
            const float b0 = bias[nb + 0], b1 = bias[nb + 1];
            const float b2 = bias[nb + 2], b3 = bias[nb + 3];
            const int h = nb >> 4, d0 = nb & 15;
            #pragma unroll
            for (int i = 0; i < 2; ++i) {
                long m = m0 + wr * 32 + i * 16 + lrow;
                if (m < NN) {
                    unsigned u0 = (unsigned)f2bf(acc[i][j][0] + b0) | ((unsigned)f2bf(acc[i][j][1] + b1) << 16);
                    unsigned u1 = (unsigned)f2bf(acc[i][j][2] + b2) | ((unsigned)f2bf(acc[i][j][3] + b3) << 16);
                    *(uint2*)&kv[m * 128 + h * 16 + slotu + (d0 >> 1)] = make_uint2(u0, u1);
                }
            }
        }
    }
}

// ---------- MFMA bf16 output GEMM: out = (t/4)@Wa^T + ba, skip-gated ----------
__global__ __launch_bounds__(256) void mfma_out(
    const float* __restrict__ T, const float* __restrict__ Wa, const float* __restrict__ ba,
    float* __restrict__ out, const float* __restrict__ skip, const float* __restrict__ xres)
{
    const int tid = threadIdx.x;
    const int lane = tid & 63;
    const int wave = tid >> 6;
    const int wr = wave >> 1;
    const int wc = wave & 1;
    const long m0 = (long)blockIdx.x * 64;

    __shared__ short Xs[64 * PAD_K];
    __shared__ short Wsh[128 * PAD_K];

    #pragma unroll
    for (int i = 0; i < 8; ++i) {
        int f = tid + 256 * i;
        int row = f >> 5, c4 = f & 31;
        long m = m0 + row;
        float4 v = make_float4(0.f, 0.f, 0.f, 0.f);
        if (m < NN) v = ((const float4*)(T + m * DD))[c4];
        // fold cross-relation mean (1/4, exact in bf16) into the conversion
        unsigned u0 = (unsigned)f2bf(v.x * 0.25f) | ((unsigned)f2bf(v.y * 0.25f) << 16);
        unsigned u1 = (unsigned)f2bf(v.z * 0.25f) | ((unsigned)f2bf(v.w * 0.25f) << 16);
        *(uint2*)&Xs[row * PAD_K + c4 * 4] = make_uint2(u0, u1);
    }
    #pragma unroll
    for (int i = 0; i < 16; ++i) {
        int f = tid + 256 * i;
        int row = f >> 5, c4 = f & 31;
        float4 v = ((const float4*)(Wa + row * DD))[c4];
        unsigned u0 = (unsigned)f2bf(v.x) | ((unsigned)f2bf(v.y) << 16);
        unsigned u1 = (unsigned)f2bf(v.z) | ((unsigned)f2bf(v.w) << 16);
        *(uint2*)&Wsh[row * PAD_K + c4 * 4] = make_uint2(u0, u1);
    }
    __syncthreads();

    const int lrow = lane & 15;
    const int kg = lane >> 4;

    f32x4 acc[2][4];
    #pragma unroll
    for (int i = 0; i < 2; ++i)
        #pragma unroll
        for (int j = 0; j < 4; ++j) acc[i][j] = (f32x4){0.f, 0.f, 0.f, 0.f};

    #pragma unroll
    for (int ks = 0; ks < 4; ++ks) {
        const int kk = ks * 32 + kg * 8;
        bf16x8 xf[2], wf[4];
        #pragma unroll
        for (int i = 0; i < 2; ++i)
            xf[i] = *(const bf16x8*)&Xs[(wr * 32 + i * 16 + lrow) * PAD_K + kk];
        #pragma unroll
        for (int j = 0; j < 4; ++j)
            wf[j] = *(const bf16x8*)&Wsh[(wc * 64 + j * 16 + lrow) * PAD_K + kk];
        #pragma unroll
        for (int i = 0; i < 2; ++i)
            #pragma unroll
            for (int j = 0; j < 4; ++j)
                acc[i][j] = __builtin_amdgcn_mfma_f32_16x16x32_bf16(xf[i], wf[j], acc[i][j], 0, 0, 0);
    }

    const float s = 1.f / (1.f + __expf(-skip[0]));
    const float al = s, bt = 1.f - s;

    #pragma unroll
    for (int j = 0; j < 4; ++j) {
        const int n = wc * 64 + j * 16 + lrow;
        const float bcol = ba[n];
        #pragma unroll
        for (int i = 0; i < 2; ++i) {
            #pragma unroll
            for (int r = 0; r < 4; ++r) {
                long m = m0 + wr * 32 + i * 16 + kg * 4 + r;
                if (m < NN) {
                    long o = m * DD + n;
                    out[o] = __builtin_fmaf(xres[o], bt, (acc[i][j][r] + bcol) * al);
                }
            }
        }
    }
}

// ---------- CSR build: histogram -> scan -> fill ----------
// offs[] is IMMUTABLE after scan; csr_fill bumps cur[].

__global__ __launch_bounds__(256) void csr_hist(
    const int* __restrict__ edst, int* __restrict__ cnt)
{
    int idx = blockIdx.x * 256 + threadIdx.x;
    if (idx >= NEDGE) return;
    int r = idx / EE;
    atomicAdd(&cnt[r * NN + edst[idx]], 1);
}

__global__ __launch_bounds__(SCAN_BLK) void scan1(
    const int* __restrict__ cnt, int* __restrict__ offs, int* __restrict__ bsum)
{
    __shared__ int sh[SCAN_BLK];
    int blk = blockIdx.x, tid = threadIdx.x;
    int base = blk * SCAN_ELEMS + tid * 4;
    int v0 = 0, v1 = 0, v2 = 0, v3 = 0;
    if (base + 3 < NSEG) {
        int4 t = *(const int4*)(cnt + base);
        v0 = t.x; v1 = t.y; v2 = t.z; v3 = t.w;
    } else {
        if (base + 0 < NSEG) v0 = cnt[base + 0];
        if (base + 1 < NSEG) v1 = cnt[base + 1];
        if (base + 2 < NSEG) v2 = cnt[base + 2];
        if (base + 3 < NSEG) v3 = cnt[base + 3];
    }
    int tsum = v0 + v1 + v2 + v3;
    sh[tid] = tsum;
    __syncthreads();
    #pragma unroll
    for (int d = 1; d < SCAN_BLK; d <<= 1) {
        int x = (tid >= d) ? sh[tid - d] : 0;
        __syncthreads();
        sh[tid] += x;
        __syncthreads();
    }
    int excl = sh[tid] - tsum;
    int r0 = excl, r1 = r0 + v0, r2 = r1 + v1, r3 = r2 + v2;
    if (base + 3 < NSEG) {
        *(int4*)(offs + base) = make_int4(r0, r1, r2, r3);
    } else {
        if (base + 0 < NSEG) offs[base + 0] = r0;
        if (base + 1 < NSEG) offs[base + 1] = r1;
        if (base + 2 < NSEG) offs[base + 2] = r2;
        if (base + 3 < NSEG) offs[base + 3] = r3;
    }
    if (tid == SCAN_BLK - 1) bsum[blk] = sh[tid];
}

__global__ __launch_bounds__(512) void scan2(int* __restrict__ bsum)
{
    __shared__ int sh[512];
    int tid = threadIdx.x;
    int v = (tid < SCAN_NB) ? bsum[tid] : 0;
    sh[tid] = v;
    __syncthreads();
    #pragma unroll
    for (int d = 1; d < 512; d <<= 1) {
        int x = (tid >= d) ? sh[tid - d] : 0;
        __syncthreads();
        sh[tid] += x;
        __syncthreads();
    }
    if (tid < SCAN_NB) bsum[tid] = sh[tid] - v;   // exclusive block sums
}

__global__ __launch_bounds__(SCAN_BLK) void scan3(
    int* __restrict__ offs, int* __restrict__ cur, const int* __restrict__ bsum)
{
    int blk = blockIdx.x;
    int add = bsum[blk];
    int base = blk * SCAN_ELEMS + threadIdx.x * 4;
    #pragma unroll
    for (int j = 0; j < 4; ++j)
        if (base + j < NSEG) {
            int v = offs[base + j] + add;
            offs[base + j] = v;
            cur[base + j] = v;
        }
}

__global__ __launch_bounds__(256) void csr_fill(
    const int* __restrict__ esrc, const int* __restrict__ edst,
    int* __restrict__ cur, int* __restrict__ csr_src)
{
    int idx = blockIdx.x * 256 + threadIdx.x;
    if (idx >= NEDGE) return;
    int r = idx / EE;
    int pos = atomicAdd(&cur[r * NN + edst[idx]], 1);
    csr_src[pos] = esrc[idx];
}

// ---------- fused per-dst gather ----------
// thread = (dst,h). A/M staged in LDS as packed bf16 (33.8 KB): lanes sharing
// h broadcast-read; the 8 h-matrices (528 B stride, = 16 mod 128) hit all 32
// banks exactly once per b128 read -> conflict-free. Plain exp (shift-
// invariant softmax, |att| << 88).
#define GT 512
__global__ __launch_bounds__(GT) void gather_agg(
    const unsigned* __restrict__ kv, const float* __restrict__ q,
    const int* __restrict__ csr_src, const int* __restrict__ offs,
    const float* __restrict__ rel_att, const float* __restrict__ rel_msg,
    const float* __restrict__ rel_pri, float* __restrict__ t)
{
    __shared__ unsigned As[32 * MAT_U];
    __shared__ unsigned Ms[32 * MAT_U];
    const int tid = threadIdx.x;
    #pragma unroll
    for (int i = 0; i < (32 * 128) / GT; ++i) {
        int f = tid + GT * i;
        int m = f >> 7, j = f & 127;
        float2 a = *(const float2*)(rel_att + m * 256 + j * 2);
        float2 b = *(const float2*)(rel_msg + m * 256 + j * 2);
        As[m * MAT_U + j] = (unsigned)f2bf(a.x) | ((unsigned)f2bf(a.y) << 16);
        Ms[m * MAT_U + j] = (unsigned)f2bf(b.x) | ((unsigned)f2bf(b.y) << 16);
    }
    __syncthreads();

    int gidx = blockIdx.x * GT + tid;
    if (gidx >= NN * HH) return;
    const int dst = gidx >> 3, h = gidx & 7;

    float qh[16];
    {
        const float4* qp = (const float4*)(q + (long)dst * DD + h * DK);
        #pragma unroll
        for (int i = 0; i < 4; ++i) {
            float4 a = qp[i];
            qh[4*i] = a.x; qh[4*i+1] = a.y; qh[4*i+2] = a.z; qh[4*i+3] = a.w;
        }
    }

    float tacc[16];
    #pragma unroll
    for (int f = 0; f < 16; ++f) tacc[f] = 0.f;

    for (int r = 0; r < RR; ++r) {
        const int seg = r * NN + dst;
        const int beg = offs[seg];
        const int end = (seg == NSEG - 1) ? NEDGE : offs[seg + 1];
        if (end <= beg) continue;                 // empty mailbox contributes 0

        const unsigned* A = &As[(r * HH + h) * MAT_U];
        const unsigned* M = &Ms[(r * HH + h) * MAT_U];
        const float pri = rel_pri[r * HH + h] * 0.25f;   // pri / sqrt(dk)

        float qbar[16];
        #pragma unroll
        for (int d = 0; d < 16; ++d) {
            uint4 r0 = *(const uint4*)&A[d * 8];
            uint4 r1 = *(const uint4*)&A[d * 8 + 4];
            float acc = bflo(r0.x) * qh[0];
            acc = __builtin_fmaf(bfhi(r0.x), qh[1], acc);
            acc = __builtin_fmaf(bflo(r0.y), qh[2], acc);
            acc = __builtin_fmaf(bfhi(r0.y), qh[3], acc);
            acc = __builtin_fmaf(bflo(r0.z), qh[4], acc);
            acc = __builtin_fmaf(bfhi(r0.z), qh[5], acc);
            acc = __builtin_fmaf(bflo(r0.w), qh[6], acc);
            acc = __builtin_fmaf(bfhi(r0.w), qh[7], acc);
            acc = __builtin_fmaf(bflo(r1.x), qh[8], acc);
            acc = __builtin_fmaf(bfhi(r1.x), qh[9], acc);
            acc = __builtin_fmaf(bflo(r1.y), qh[10], acc);
            acc = __builtin_fmaf(bfhi(r1.y), qh[11], acc);
            acc = __builtin_fmaf(bflo(r1.z), qh[12], acc);
            acc = __builtin_fmaf(bfhi(r1.z), qh[13], acc);
            acc = __builtin_fmaf(bflo(r1.w), qh[14], acc);
            acc = __builtin_fmaf(bfhi(r1.w), qh[15], acc);
            qbar[d] = acc * pri;                  // fold pri/sqrt(dk) into qbar
        }

        float s = 0.f;
        float vb[16];
        #pragma unroll
        for (int f = 0; f < 16; ++f) vb[f] = 0.f;

        for (int e = beg; e < end; ++e) {
            int src = csr_src[e];
            const uint4* kvp = (const uint4*)kv + ((long)src * 32 + h * 4);
            uint4 ka = kvp[0], kb = kvp[1];
            uint4 va = kvp[2], vc = kvp[3];

            float att;
            att  = bflo(ka.x) * qbar[0];
            att = __builtin_fmaf(bfhi(ka.x), qbar[1], att);
            att = __builtin_fmaf(bflo(ka.y), qbar[2], att);
            att = __builtin_fmaf(bfhi(ka.y), qbar[3], att);
            att = __builtin_fmaf(bflo(ka.z), qbar[4], att);
            att = __builtin_fmaf(bfhi(ka.z), qbar[5], att);
            att = __builtin_fmaf(bflo(ka.w), qbar[6], att);
            att = __builtin_fmaf(bfhi(ka.w), qbar[7], att);
            att = __builtin_fmaf(bflo(kb.x), qbar[8], att);
            att = __builtin_fmaf(bfhi(kb.x), qbar[9], att);
            att = __builtin_fmaf(bflo(kb.y), qbar[10], att);
            att = __builtin_fmaf(bfhi(kb.y), qbar[11], att);
            att = __builtin_fmaf(bflo(kb.z), qbar[12], att);
            att = __builtin_fmaf(bfhi(kb.z), qbar[13], att);
            att = __builtin_fmaf(bflo(kb.w), qbar[14], att);
            att = __builtin_fmaf(bfhi(kb.w), qbar[15], att);

            float ea = __expf(att);
            s += ea;
            vb[0]  = __builtin_fmaf(ea, bflo(va.x), vb[0]);
            vb[1]  = __builtin_fmaf(ea, bfhi(va.x), vb[1]);
            vb[2]  = __builtin_fmaf(ea, bflo(va.y), vb[2]);
            vb[3]  = __builtin_fmaf(ea, bfhi(va.y), vb[3]);
            vb[4]  = __builtin_fmaf(ea, bflo(va.z), vb[4]);
            vb[5]  = __builtin_fmaf(ea, bfhi(va.z), vb[5]);
            vb[6]  = __builtin_fmaf(ea, bflo(va.w), vb[6]);
            vb[7]  = __builtin_fmaf(ea, bfhi(va.w), vb[7]);
            vb[8]  = __builtin_fmaf(ea, bflo(vc.x), vb[8]);
            vb[9]  = __builtin_fmaf(ea, bfhi(vc.x), vb[9]);
            vb[10] = __builtin_fmaf(ea, bflo(vc.y), vb[10]);
            vb[11] = __builtin_fmaf(ea, bfhi(vc.y), vb[11]);
            vb[12] = __builtin_fmaf(ea, bflo(vc.z), vb[12]);
            vb[13] = __builtin_fmaf(ea, bfhi(vc.z), vb[13]);
            vb[14] = __builtin_fmaf(ea, bflo(vc.w), vb[14]);
            vb[15] = __builtin_fmaf(ea, bfhi(vc.w), vb[15]);
        }

        float inv = 1.f / s;
        float u[16];
        #pragma unroll
        for (int f = 0; f < 16; ++f) u[f] = 0.f;
        #pragma unroll
        for (int d = 0; d < 16; ++d) {
            float vd = vb[d];
            uint4 m0 = *(const uint4*)&M[d * 8];
            uint4 m1 = *(const uint4*)&M[d * 8 + 4];
            u[0]  = __builtin_fmaf(vd, bflo(m0.x), u[0]);
            u[1]  = __builtin_fmaf(vd, bfhi(m0.x), u[1]);
            u[2]  = __builtin_fmaf(vd, bflo(m0.y), u[2]);
            u[3]  = __builtin_fmaf(vd, bfhi(m0.y), u[3]);
            u[4]  = __builtin_fmaf(vd, bflo(m0.z), u[4]);
            u[5]  = __builtin_fmaf(vd, bfhi(m0.z), u[5]);
            u[6]  = __builtin_fmaf(vd, bflo(m0.w), u[6]);
            u[7]  = __builtin_fmaf(vd, bfhi(m0.w), u[7]);
            u[8]  = __builtin_fmaf(vd, bflo(m1.x), u[8]);
            u[9]  = __builtin_fmaf(vd, bfhi(m1.x), u[9]);
            u[10] = __builtin_fmaf(vd, bflo(m1.y), u[10]);
            u[11] = __builtin_fmaf(vd, bfhi(m1.y), u[11]);
            u[12] = __builtin_fmaf(vd, bflo(m1.z), u[12]);
            u[13] = __builtin_fmaf(vd, bfhi(m1.z), u[13]);
            u[14] = __builtin_fmaf(vd, bflo(m1.w), u[14]);
            u[15] = __builtin_fmaf(vd, bfhi(m1.w), u[15]);
        }
        #pragma unroll
        for (int f = 0; f < 16; ++f)
            tacc[f] = __builtin_fmaf(u[f], inv, tacc[f]);
    }

    float* tp = t + (long)dst * DD + h * DK;
    #pragma unroll
    for (int i = 0; i < 4; ++i) {
        float4 o;
        o.x = tacc[4*i]; o.y = tacc[4*i+1]; o.z = tacc[4*i+2]; o.w = tacc[4*i+3];
        *(float4*)(tp + 4 * i) = o;
    }
}

extern "C" void kernel_launch(void* const* d_in, const int* in_sizes, int n_in,
                              void* d_out, int out_size, void* d_ws, size_t ws_size,
                              hipStream_t stream)
{
    const float* x   = (const float*)d_in[0];
    const int* esrc  = (const int*)d_in[1];
    const int* edst  = (const int*)d_in[2];
    const float* Wk  = (const float*)d_in[3];
    const float* bk  = (const float*)d_in[4];
    const float* Wq  = (const float*)d_in[5];
    const float* bq  = (const float*)d_in[6];
    const float* Wv  = (const float*)d_in[7];
    const float* bv  = (const float*)d_in[8];
    const float* Wa  = (const float*)d_in[9];
    const float* ba  = (const float*)d_in[10];
    const float* rel_att = (const float*)d_in[11];
    const float* rel_msg = (const float*)d_in[12];
    const float* rel_pri = (const float*)d_in[13];
    const float* skip    = (const float*)d_in[14];
    float* out = (float*)d_out;

    // ws: [q:ND][t:ND][kv:ND uints] [cnt:NSEG][offs:NSEG][cur:NSEG][bsum:512][csr:NEDGE]
    float* ws = (float*)d_ws;
    const long ND = (long)NN * DD;
    float* qbuf = ws;
    float* tbuf = ws + ND;
    unsigned* kvb = (unsigned*)(ws + 2 * ND);
    int* cnt  = (int*)(ws + 3 * ND);
    int* offs = cnt + NSEG;
    int* cur  = offs + NSEG;
    int* bsum = cur + NSEG;
    int* csr  = bsum + 512;

    hipMemsetAsync(cnt, 0, NSEG * sizeof(int), stream);

    const int gb = (NN + 63) / 64;   // 1563
    mfma_qkv<<<dim3(gb, 3), 256, 0, stream>>>(x, Wq, Wk, Wv, bq, bk, bv, qbuf, kvb);

    const int ebk = (NEDGE + 255) / 256;
    csr_hist<<<ebk, 256, 0, stream>>>(edst, cnt);
    scan1<<<SCAN_NB, SCAN_BLK, 0, stream>>>(cnt, offs, bsum);
    scan2<<<1, 512, 0, stream>>>(bsum);
    scan3<<<SCAN_NB, SCAN_BLK, 0, stream>>>(offs, cur, bsum);
    csr_fill<<<ebk, 256, 0, stream>>>(esrc, edst, cur, csr);

    gather_agg<<<(NN * HH + GT - 1) / GT, GT, 0, stream>>>(
        kvb, qbuf, csr, offs, rel_att, rel_msg, rel_pri, tbuf);

    mfma_out<<<gb, 256, 0, stream>>>(tbuf, Wa, ba, out, skip, x);
}

// Round 9
// 335.180 us; speedup vs baseline: 2.4724x; 1.0910x over previous
//
#include <hip/hip_runtime.h>

#define NN 100000
#define DD 128
#define RR 4
#define EE 150000
#define HH 8
#define DK 16

#define NSEG (RR * NN)        // 400000
#define NEDGE (RR * EE)       // 600000
#define SCAN_BLK 256
#define SCAN_ELEMS 1024
#define SCAN_NB ((NSEG + SCAN_ELEMS - 1) / SCAN_ELEMS)   // 391
#define PAD_K 136             // bf16 row stride for MFMA LDS tiles
#define MAT_U 132             // uints per 16x16 bf16 matrix (528 B stride)
#define ND2 (NN * 64)         // uints per packed bf16 [node][128] buffer

typedef short bf16x8 __attribute__((ext_vector_type(8)));
typedef float f32x4  __attribute__((ext_vector_type(4)));

// f32 -> bf16 round-to-nearest-even (bit pattern as ushort)
__device__ __forceinline__ unsigned short f2bf(float f) {
    unsigned u = __float_as_uint(f);
    return (unsigned short)((u + 0x7fffu + ((u >> 16) & 1u)) >> 16);
}
__device__ __forceinline__ float bflo(unsigned w) { return __uint_as_float(w << 16); }
__device__ __forceinline__ float bfhi(unsigned w) { return __uint_as_float(w & 0xffff0000u); }

// ---------- prep: W_msg[r] = M[r,h]^T-combined Wv, b_msg likewise ----------
// W_msg[r][h*16+f][c] = sum_d M[r,h][d][f] * Wv[h*16+d][c]
__global__ __launch_bounds__(128) void prep_wmsg(
    const float* __restrict__ Wv, const float* __restrict__ bv,
    const float* __restrict__ rel_msg,
    float* __restrict__ Wm, float* __restrict__ bm)
{
    const int b = blockIdx.x;          // r*8 + h
    const int r = b >> 3, h = b & 7;
    const int c = threadIdx.x;         // 0..127
    __shared__ float Msh[256];
    for (int i = c; i < 256; i += 128) Msh[i] = rel_msg[(b << 8) + i];
    __syncthreads();

    #pragma unroll 4
    for (int f = 0; f < 16; ++f) {
        float acc = 0.f;
        #pragma unroll
        for (int d = 0; d < 16; ++d)
            acc = __builtin_fmaf(Msh[d * 16 + f], Wv[(h * 16 + d) * DD + c], acc);
        Wm[((long)r * DD + h * 16 + f) * DD + c] = acc;
    }
    if (c < 16) {
        float acc = 0.f;
        #pragma unroll
        for (int d = 0; d < 16; ++d)
            acc = __builtin_fmaf(Msh[d * 16 + c], bv[h * 16 + d], acc);
        bm[r * DD + h * 16 + c] = acc;
    }
}

// ---------- MFMA projections (grid.y = 6 matrices) ----------
// Tile: 64 X-rows x 128 out-dims, 4 waves 2x2, proven barrier structure.
// ALL mats use swapped-operand D = W*X^T so each lane holds 4 consecutive
// out-dims -> pack bf16 pairs into out[node][128] bf16 (64 uints/row).
// mat 0: k (Wk,bk)  mat 1: q (Wq,bq)  mat 2+r: vM[r] (Wm[r],bm[r]).
__global__ __launch_bounds__(256) void mfma_proj(
    const float* __restrict__ X,
    const float* __restrict__ Wk, const float* __restrict__ Wq, const float* __restrict__ Wm,
    const float* __restrict__ bk, const float* __restrict__ bq, const float* __restrict__ bm,
    unsigned* __restrict__ kb, unsigned* __restrict__ qb, unsigned* __restrict__ vMb)
{
    const int tid = threadIdx.x;
    const int lane = tid & 63;
    const int wave = tid >> 6;
    const int wr = wave >> 1;
    const int wc = wave & 1;
    const long m0 = (long)blockIdx.x * 64;
    const int mat = blockIdx.y;
    const float* W    = (mat == 0) ? Wk : (mat == 1) ? Wq : (Wm + (long)(mat - 2) * DD * DD);
    const float* bias = (mat == 0) ? bk : (mat == 1) ? bq : (bm + (mat - 2) * DD);
    unsigned* out     = (mat == 0) ? kb : (mat == 1) ? qb : (vMb + (long)(mat - 2) * ND2);

    __shared__ short Xs[64 * PAD_K];
    __shared__ short Wsh[128 * PAD_K];

    #pragma unroll
    for (int i = 0; i < 8; ++i) {
        int f = tid + 256 * i;
        int row = f >> 5, c4 = f & 31;
        long m = m0 + row;
        float4 v = make_float4(0.f, 0.f, 0.f, 0.f);
        if (m < NN) v = ((const float4*)(X + m * DD))[c4];
        unsigned u0 = (unsigned)f2bf(v.x) | ((unsigned)f2bf(v.y) << 16);
        unsigned u1 = (unsigned)f2bf(v.z) | ((unsigned)f2bf(v.w) << 16);
        *(uint2*)&Xs[row * PAD_K + c4 * 4] = make_uint2(u0, u1);
    }
    #pragma unroll
    for (int i = 0; i < 16; ++i) {
        int f = tid + 256 * i;
        int row = f >> 5, c4 = f & 31;
        float4 v = ((const float4*)(W + row * DD))[c4];
        unsigned u0 = (unsigned)f2bf(v.x) | ((unsigned)f2bf(v.y) << 16);
        unsigned u1 = (unsigned)f2bf(v.z) | ((unsigned)f2bf(v.w) << 16);
        *(uint2*)&Wsh[row * PAD_K + c4 * 4] = make_uint2(u0, u1);
    }
    __syncthreads();

    const int lrow = lane & 15;
    const int kg = lane >> 4;

    f32x4 acc[2][4];
    #pragma unroll
    for (int i = 0; i < 2; ++i)
        #pragma unroll
        for (int j = 0; j < 4; ++j) acc[i][j] = (f32x4){0.f, 0.f, 0.f, 0.f};

    #pragma unroll
    for (int ks = 0; ks < 4; ++ks) {
        const int kk = ks * 32 + kg * 8;
        bf16x8 xf[2], wf[4];
        #pragma unroll
        for (int i = 0; i < 2; ++i)
            xf[i] = *(const bf16x8*)&Xs[(wr * 32 + i * 16 + lrow) * PAD_K + kk];
        #pragma unroll
        for (int j = 0; j < 4; ++j)
            wf[j] = *(const bf16x8*)&Wsh[(wc * 64 + j * 16 + lrow) * PAD_K + kk];
        #pragma unroll
        for (int i = 0; i < 2; ++i)
            #pragma unroll
            for (int j = 0; j < 4; ++j)
                acc[i][j] = __builtin_amdgcn_mfma_f32_16x16x32_bf16(wf[j], xf[i], acc[i][j], 0, 0, 0);
    }

    // D rows = out-dims (4 consecutive per lane), D cols = X rows m
    #pragma unroll
    for (int j = 0; j < 4; ++j) {
        const int nb = wc * 64 + j * 16 + kg * 4;
        const float b0 = bias[nb + 0], b1 = bias[nb + 1];
        const float b2 = bias[nb + 2], b3 = bias[nb + 3];
        #pragma unroll
        for (int i = 0; i < 2; ++i) {
            long m = m0 + wr * 32 + i * 16 + lrow;
            if (m < NN) {
                unsigned u0 = (unsigned)f2bf(acc[i][j][0] + b0) | ((unsigned)f2bf(acc[i][j][1] + b1) << 16);
                unsigned u1 = (unsigned)f2bf(acc[i][j][2] + b2) | ((unsigned)f2bf(acc[i][j][3] + b3) << 16);
                *(uint2*)&out[m * 64 + (nb >> 1)] = make_uint2(u0, u1);
            }
        }
    }
}

// ---------- MFMA bf16 output GEMM: out = (t/4)@Wa^T + ba, skip-gated ----------
__global__ __launch_bounds__(256) void mfma_out(
    const float* __restrict__ T, const float* __restrict__ Wa, const float* __restrict__ ba,
    float* __restrict__ out, const float* __restrict__ skip, const float* __restrict__ xres)
{
    const int tid = threadIdx.x;
    const int lane = tid & 63;
    const int wave = tid >> 6;
    const int wr = wave >> 1;
    const int wc = wave & 1;
    const long m0 = (long)blockIdx.x * 64;

    __shared__ short Xs[64 * PAD_K];
    __shared__ short Wsh[128 * PAD_K];

    #pragma unroll
    for (int i = 0; i < 8; ++i) {
        int f = tid + 256 * i;
        int row = f >> 5, c4 = f & 31;
        long m = m0 + row;
        float4 v = make_float4(0.f, 0.f, 0.f, 0.f);
        if (m < NN) v = ((const float4*)(T + m * DD))[c4];
        unsigned u0 = (unsigned)f2bf(v.x * 0.25f) | ((unsigned)f2bf(v.y * 0.25f) << 16);
        unsigned u1 = (unsigned)f2bf(v.z * 0.25f) | ((unsigned)f2bf(v.w * 0.25f) << 16);
        *(uint2*)&Xs[row * PAD_K + c4 * 4] = make_uint2(u0, u1);
    }
    #pragma unroll
    for (int i = 0; i < 16; ++i) {
        int f = tid + 256 * i;
        int row = f >> 5, c4 = f & 31;
        float4 v = ((const float4*)(Wa + row * DD))[c4];
        unsigned u0 = (unsigned)f2bf(v.x) | ((unsigned)f2bf(v.y) << 16);
        unsigned u1 = (unsigned)f2bf(v.z) | ((unsigned)f2bf(v.w) << 16);
        *(uint2*)&Wsh[row * PAD_K + c4 * 4] = make_uint2(u0, u1);
    }
    __syncthreads();

    const int lrow = lane & 15;
    const int kg = lane >> 4;

    f32x4 acc[2][4];
    #pragma unroll
    for (int i = 0; i < 2; ++i)
        #pragma unroll
        for (int j = 0; j < 4; ++j) acc[i][j] = (f32x4){0.f, 0.f, 0.f, 0.f};

    #pragma unroll
    for (int ks = 0; ks < 4; ++ks) {
        const int kk = ks * 32 + kg * 8;
        bf16x8 xf[2], wf[4];
        #pragma unroll
        for (int i = 0; i < 2; ++i)
            xf[i] = *(const bf16x8*)&Xs[(wr * 32 + i * 16 + lrow) * PAD_K + kk];
        #pragma unroll
        for (int j = 0; j < 4; ++j)
            wf[j] = *(const bf16x8*)&Wsh[(wc * 64 + j * 16 + lrow) * PAD_K + kk];
        #pragma unroll
        for (int i = 0; i < 2; ++i)
            #pragma unroll
            for (int j = 0; j < 4; ++j)
                acc[i][j] = __builtin_amdgcn_mfma_f32_16x16x32_bf16(xf[i], wf[j], acc[i][j], 0, 0, 0);
    }

    const float s = 1.f / (1.f + __expf(-skip[0]));
    const float al = s, bt = 1.f - s;

    #pragma unroll
    for (int j = 0; j < 4; ++j) {
        const int n = wc * 64 + j * 16 + lrow;
        const float bcol = ba[n];
        #pragma unroll
        for (int i = 0; i < 2; ++i) {
            #pragma unroll
            for (int r = 0; r < 4; ++r) {
                long m = m0 + wr * 32 + i * 16 + kg * 4 + r;
                if (m < NN) {
                    long o = m * DD + n;
                    out[o] = __builtin_fmaf(xres[o], bt, (acc[i][j][r] + bcol) * al);
                }
            }
        }
    }
}

// ---------- CSR build: histogram -> scan -> fill ----------

__global__ __launch_bounds__(256) void csr_hist(
    const int* __restrict__ edst, int* __restrict__ cnt)
{
    int idx = blockIdx.x * 256 + threadIdx.x;
    if (idx >= NEDGE) return;
    int r = idx / EE;
    atomicAdd(&cnt[r * NN + edst[idx]], 1);
}

__global__ __launch_bounds__(SCAN_BLK) void scan1(
    const int* __restrict__ cnt, int* __restrict__ offs, int* __restrict__ bsum)
{
    __shared__ int sh[SCAN_BLK];
    int blk = blockIdx.x, tid = threadIdx.x;
    int base = blk * SCAN_ELEMS + tid * 4;
    int v0 = 0, v1 = 0, v2 = 0, v3 = 0;
    if (base + 3 < NSEG) {
        int4 t = *(const int4*)(cnt + base);
        v0 = t.x; v1 = t.y; v2 = t.z; v3 = t.w;
    } else {
        if (base + 0 < NSEG) v0 = cnt[base + 0];
        if (base + 1 < NSEG) v1 = cnt[base + 1];
        if (base + 2 < NSEG) v2 = cnt[base + 2];
        if (base + 3 < NSEG) v3 = cnt[base + 3];
    }
    int tsum = v0 + v1 + v2 + v3;
    sh[tid] = tsum;
    __syncthreads();
    #pragma unroll
    for (int d = 1; d < SCAN_BLK; d <<= 1) {
        int x = (tid >= d) ? sh[tid - d] : 0;
        __syncthreads();
        sh[tid] += x;
        __syncthreads();
    }
    int excl = sh[tid] - tsum;
    int r0 = excl, r1 = r0 + v0, r2 = r1 + v1, r3 = r2 + v2;
    if (base + 3 < NSEG) {
        *(int4*)(offs + base) = make_int4(r0, r1, r2, r3);
    } else {
        if (base + 0 < NSEG) offs[base + 0] = r0;
        if (base + 1 < NSEG) offs[base + 1] = r1;
        if (base + 2 < NSEG) offs[base + 2] = r2;
        if (base + 3 < NSEG) offs[base + 3] = r3;
    }
    if (tid == SCAN_BLK - 1) bsum[blk] = sh[tid];
}

__global__ __launch_bounds__(512) void scan2(int* __restrict__ bsum)
{
    __shared__ int sh[512];
    int tid = threadIdx.x;
    int v = (tid < SCAN_NB) ? bsum[tid] : 0;
    sh[tid] = v;
    __syncthreads();
    #pragma unroll
    for (int d = 1; d < 512; d <<= 1) {
        int x = (tid >= d) ? sh[tid - d] : 0;
        __syncthreads();
        sh[tid] += x;
        __syncthreads();
    }
    if (tid < SCAN_NB) bsum[tid] = sh[tid] - v;
}

__global__ __launch_bounds__(SCAN_BLK) void scan3(
    int* __restrict__ offs, int* __restrict__ cur, const int* __restrict__ bsum)
{
    int blk = blockIdx.x;
    int add = bsum[blk];
    int base = blk * SCAN_ELEMS + threadIdx.x * 4;
    #pragma unroll
    for (int j = 0; j < 4; ++j)
        if (base + j < NSEG) {
            int v = offs[base + j] + add;
            offs[base + j] = v;
            cur[base + j] = v;
        }
}

__global__ __launch_bounds__(256) void csr_fill(
    const int* __restrict__ esrc, const int* __restrict__ edst,
    int* __restrict__ cur, int* __restrict__ csr_src)
{
    int idx = blockIdx.x * 256 + threadIdx.x;
    if (idx >= NEDGE) return;
    int r = idx / EE;
    int pos = atomicAdd(&cur[r * NN + edst[idx]], 1);
    csr_src[pos] = esrc[idx];
}

// ---------- fused per-dst gather ----------
// thread = (dst,h). A (rel_att) staged bf16 in LDS (16.9 KB) + pri.
// Per relation: qbar = A@q (pri folded) once; edge loop reads k 32B + vM 32B;
// vb accumulates exp(att)*vM directly (M matvec precomputed into vM).
#define GT 512
__global__ __launch_bounds__(GT) void gather_agg(
    const unsigned* __restrict__ kb, const unsigned* __restrict__ qbuf,
    const unsigned* __restrict__ vMb,
    const int* __restrict__ csr_src, const int* __restrict__ offs,
    const float* __restrict__ rel_att, const float* __restrict__ rel_pri,
    float* __restrict__ t)
{
    __shared__ unsigned As[32 * MAT_U];
    __shared__ float prish[32];
    const int tid = threadIdx.x;
    #pragma unroll
    for (int i = 0; i < (32 * 128) / GT; ++i) {
        int f = tid + GT * i;
        int m = f >> 7, j = f & 127;
        float2 a = *(const float2*)(rel_att + m * 256 + j * 2);
        As[m * MAT_U + j] = (unsigned)f2bf(a.x) | ((unsigned)f2bf(a.y) << 16);
    }
    if (tid < 32) prish[tid] = rel_pri[tid] * 0.25f;
    __syncthreads();

    int gidx = blockIdx.x * GT + tid;
    if (gidx >= NN * HH) return;
    const int dst = gidx >> 3, h = gidx & 7;

    float qh[16];
    {
        const uint4* qp = (const uint4*)(qbuf + (long)dst * 64 + h * 8);
        uint4 qa = qp[0], qc = qp[1];
        qh[0] = bflo(qa.x);  qh[1] = bfhi(qa.x);
        qh[2] = bflo(qa.y);  qh[3] = bfhi(qa.y);
        qh[4] = bflo(qa.z);  qh[5] = bfhi(qa.z);
        qh[6] = bflo(qa.w);  qh[7] = bfhi(qa.w);
        qh[8] = bflo(qc.x);  qh[9] = bfhi(qc.x);
        qh[10] = bflo(qc.y); qh[11] = bfhi(qc.y);
        qh[12] = bflo(qc.z); qh[13] = bfhi(qc.z);
        qh[14] = bflo(qc.w); qh[15] = bfhi(qc.w);
    }

    float tacc[16];
    #pragma unroll
    for (int f = 0; f < 16; ++f) tacc[f] = 0.f;

    for (int r = 0; r < RR; ++r) {
        const int seg = r * NN + dst;
        const int beg = offs[seg];
        const int end = (seg == NSEG - 1) ? NEDGE : offs[seg + 1];
        if (end <= beg) continue;                 // empty mailbox contributes 0

        const unsigned* A = &As[(r * HH + h) * MAT_U];
        const float pri = prish[r * HH + h];

        float qbar[16];
        #pragma unroll
        for (int d = 0; d < 16; ++d) {
            uint4 r0 = *(const uint4*)&A[d * 8];
            uint4 r1 = *(const uint4*)&A[d * 8 + 4];
            float acc = bflo(r0.x) * qh[0];
            acc = __builtin_fmaf(bfhi(r0.x), qh[1], acc);
            acc = __builtin_fmaf(bflo(r0.y), qh[2], acc);
            acc = __builtin_fmaf(bfhi(r0.y), qh[3], acc);
            acc = __builtin_fmaf(bflo(r0.z), qh[4], acc);
            acc = __builtin_fmaf(bfhi(r0.z), qh[5], acc);
            acc = __builtin_fmaf(bflo(r0.w), qh[6], acc);
            acc = __builtin_fmaf(bfhi(r0.w), qh[7], acc);
            acc = __builtin_fmaf(bflo(r1.x), qh[8], acc);
            acc = __builtin_fmaf(bfhi(r1.x), qh[9], acc);
            acc = __builtin_fmaf(bflo(r1.y), qh[10], acc);
            acc = __builtin_fmaf(bfhi(r1.y), qh[11], acc);
            acc = __builtin_fmaf(bflo(r1.z), qh[12], acc);
            acc = __builtin_fmaf(bfhi(r1.z), qh[13], acc);
            acc = __builtin_fmaf(bflo(r1.w), qh[14], acc);
            acc = __builtin_fmaf(bfhi(r1.w), qh[15], acc);
            qbar[d] = acc * pri;
        }

        float s = 0.f;
        float vb[16];
        #pragma unroll
        for (int f = 0; f < 16; ++f) vb[f] = 0.f;

        const unsigned* vMr = vMb + (long)r * ND2;
        for (int e = beg; e < end; ++e) {
            int src = csr_src[e];
            const uint4* kp = (const uint4*)(kb + (long)src * 64 + h * 8);
            uint4 ka = kp[0], kc = kp[1];
            const uint4* vp = (const uint4*)(vMr + (long)src * 64 + h * 8);
            uint4 va = vp[0], vc = vp[1];

            float att;
            att  = bflo(ka.x) * qbar[0];
            att = __builtin_fmaf(bfhi(ka.x), qbar[1], att);
            att = __builtin_fmaf(bflo(ka.y), qbar[2], att);
            att = __builtin_fmaf(bfhi(ka.y), qbar[3], att);
            att = __builtin_fmaf(bflo(ka.z), qbar[4], att);
            att = __builtin_fmaf(bfhi(ka.z), qbar[5], att);
            att = __builtin_fmaf(bflo(ka.w), qbar[6], att);
            att = __builtin_fmaf(bfhi(ka.w), qbar[7], att);
            att = __builtin_fmaf(bflo(kc.x), qbar[8], att);
            att = __builtin_fmaf(bfhi(kc.x), qbar[9], att);
            att = __builtin_fmaf(bflo(kc.y), qbar[10], att);
            att = __builtin_fmaf(bfhi(kc.y), qbar[11], att);
            att = __builtin_fmaf(bflo(kc.z), qbar[12], att);
            att = __builtin_fmaf(bfhi(kc.z), qbar[13], att);
            att = __builtin_fmaf(bflo(kc.w), qbar[14], att);
            att = __builtin_fmaf(bfhi(kc.w), qbar[15], att);

            float ea = __expf(att);
            s += ea;
            vb[0]  = __builtin_fmaf(ea, bflo(va.x), vb[0]);
            vb[1]  = __builtin_fmaf(ea, bfhi(va.x), vb[1]);
            vb[2]  = __builtin_fmaf(ea, bflo(va.y), vb[2]);
            vb[3]  = __builtin_fmaf(ea, bfhi(va.y), vb[3]);
            vb[4]  = __builtin_fmaf(ea, bflo(va.z), vb[4]);
            vb[5]  = __builtin_fmaf(ea, bfhi(va.z), vb[5]);
            vb[6]  = __builtin_fmaf(ea, bflo(va.w), vb[6]);
            vb[7]  = __builtin_fmaf(ea, bfhi(va.w), vb[7]);
            vb[8]  = __builtin_fmaf(ea, bflo(vc.x), vb[8]);
            vb[9]  = __builtin_fmaf(ea, bfhi(vc.x), vb[9]);
            vb[10] = __builtin_fmaf(ea, bflo(vc.y), vb[10]);
            vb[11] = __builtin_fmaf(ea, bfhi(vc.y), vb[11]);
            vb[12] = __builtin_fmaf(ea, bflo(vc.z), vb[12]);
            vb[13] = __builtin_fmaf(ea, bfhi(vc.z), vb[13]);
            vb[14] = __builtin_fmaf(ea, bflo(vc.w), vb[14]);
            vb[15] = __builtin_fmaf(ea, bfhi(vc.w), vb[15]);
        }

        float inv = 1.f / s;
        #pragma unroll
        for (int f = 0; f < 16; ++f)
            tacc[f] = __builtin_fmaf(vb[f], inv, tacc[f]);
    }

    float* tp = t + (long)dst * DD + h * DK;
    #pragma unroll
    for (int i = 0; i < 4; ++i) {
        float4 o;
        o.x = tacc[4*i]; o.y = tacc[4*i+1]; o.z = tacc[4*i+2]; o.w = tacc[4*i+3];
        *(float4*)(tp + 4 * i) = o;
    }
}

extern "C" void kernel_launch(void* const* d_in, const int* in_sizes, int n_in,
                              void* d_out, int out_size, void* d_ws, size_t ws_size,
                              hipStream_t stream)
{
    const float* x   = (const float*)d_in[0];
    const int* esrc  = (const int*)d_in[1];
    const int* edst  = (const int*)d_in[2];
    const float* Wk  = (const float*)d_in[3];
    const float* bk  = (const float*)d_in[4];
    const float* Wq  = (const float*)d_in[5];
    const float* bq  = (const float*)d_in[6];
    const float* Wv  = (const float*)d_in[7];
    const float* bv  = (const float*)d_in[8];
    const float* Wa  = (const float*)d_in[9];
    const float* ba  = (const float*)d_in[10];
    const float* rel_att = (const float*)d_in[11];
    const float* rel_msg = (const float*)d_in[12];
    const float* rel_pri = (const float*)d_in[13];
    const float* skip    = (const float*)d_in[14];
    float* out = (float*)d_out;

    // ws (4B units): [t:ND f32][q:ND2 u][k:ND2 u][vM:4*ND2 u][Wm:4*128*128 f]
    //                [bm:512 f][cnt][offs][cur][bsum:512][csr]  ~ 212 MB
    float* ws = (float*)d_ws;
    const long ND = (long)NN * DD;
    float* tbuf = ws;
    unsigned* qb  = (unsigned*)(ws + ND);
    unsigned* kb  = qb + ND2;
    unsigned* vMb = kb + ND2;
    float* Wm = (float*)(vMb + 4L * ND2);
    float* bm = Wm + 4 * DD * DD;
    int* cnt  = (int*)(bm + 512);
    int* offs = cnt + NSEG;
    int* cur  = offs + NSEG;
    int* bsum = cur + NSEG;
    int* csr  = bsum + 512;

    hipMemsetAsync(cnt, 0, NSEG * sizeof(int), stream);

    prep_wmsg<<<32, 128, 0, stream>>>(Wv, bv, rel_msg, Wm, bm);

    const int gb = (NN + 63) / 64;   // 1563
    mfma_proj<<<dim3(gb, 6), 256, 0, stream>>>(x, Wk, Wq, Wm, bk, bq, bm, kb, qb, vMb);

    const int ebk = (NEDGE + 255) / 256;
    csr_hist<<<ebk, 256, 0, stream>>>(edst, cnt);
    scan1<<<SCAN_NB, SCAN_BLK, 0, stream>>>(cnt, offs, bsum);
    scan2<<<1, 512, 0, stream>>>(bsum);
    scan3<<<SCAN_NB, SCAN_BLK, 0, stream>>>(offs, cur, bsum);
    csr_fill<<<ebk, 256, 0, stream>>>(esrc, edst, cur, csr);

    gather_agg<<<(NN * HH + GT - 1) / GT, GT, 0, stream>>>(
        kb, qb, vMb, csr, offs, rel_att, rel_pri, tbuf);

    mfma_out<<<gb, 256, 0, stream>>>(tbuf, Wa, ba, out, skip, x);
}